// Round 16
// baseline (1710.580 us; speedup 1.0000x reference)
//
#include <hip/hip_runtime.h>

// ---------------------------------------------------------------------------
// Transformer (GateLoop-style) forward, MI355X/gfx950.  Round 16.
//  = round 15, plus LOGITS runs a ring-3 full-BK pipeline that is the exact
//    r11 kernel body with ONLY the wait changed:
//      - 3 LDS slots of a full K-step (A[256][64] 32KB + B[128][64] 16KB
//        = 48KB/slot, 144KB total -> 1 block/CU)
//      - phase t: stage(t+2) | 16 ds_read (proven swizzle) | 32 MFMA |
//        vmcnt(6) (counted: 2 K-steps in flight) | raw s_barrier
//      - distance issue->wait = 2 phases (~2400cyc) >> 900cyc HBM latency
//        (r13 failed at ~800cyc; r12 failed on 8x barrier jitter)
//    Same barrier count as r11 (1/phase vs 2 but half as many phases... 16
//    phases x 1 barrier vs 16 K-steps x 2), bitwise-identical K order.
// ---------------------------------------------------------------------------

typedef float fx4 __attribute__((ext_vector_type(4)));
typedef _Float16 f16x8 __attribute__((ext_vector_type(8)));
typedef _Float16 f16x4 __attribute__((ext_vector_type(4)));

#define AS1 __attribute__((address_space(1)))
#define AS3 __attribute__((address_space(3)))

// ---------------------------------------------------------------- transpose
__global__ __launch_bounds__(256) void transpose_f16_kernel(
    const float* __restrict__ in, _Float16* __restrict__ out,
    int K, int N, size_t ostride)
{
    __shared__ float tile[32][33];
    const int b = blockIdx.z;
    in  += (size_t)b * K * N;
    out += (size_t)b * ostride;
    const int k0 = blockIdx.x * 32, n0 = blockIdx.y * 32;
    const int tr = threadIdx.x >> 3;
    const int tc = (threadIdx.x & 7) * 4;
    fx4 v = *(const fx4*)&in[(size_t)(k0 + tr) * N + n0 + tc];
    tile[tr][tc + 0] = v[0]; tile[tr][tc + 1] = v[1];
    tile[tr][tc + 2] = v[2]; tile[tr][tc + 3] = v[3];
    __syncthreads();
    f16x4 o;
    #pragma unroll
    for (int e = 0; e < 4; ++e) o[e] = (_Float16)tile[tc + e][tr];
    *(f16x4*)&out[(size_t)(n0 + tr) * K + k0 + tc] = o;
}

// Wqkv transpose with k/v interleave
__global__ __launch_bounds__(256) void transpose_qkv_kernel(
    const float* __restrict__ in, _Float16* __restrict__ out)
{
    __shared__ float tile[32][33];
    const int b = blockIdx.z;
    in  += (size_t)b * 1024 * 3072;
    out += (size_t)b * 6144 * 1024;
    const int k0 = blockIdx.x * 32, n0 = blockIdx.y * 32;
    const int tr = threadIdx.x >> 3;
    const int tc = (threadIdx.x & 7) * 4;
    fx4 v = *(const fx4*)&in[(size_t)(k0 + tr) * 3072 + n0 + tc];
    tile[tr][tc + 0] = v[0]; tile[tr][tc + 1] = v[1];
    tile[tr][tc + 2] = v[2]; tile[tr][tc + 3] = v[3];
    __syncthreads();
    const int col = n0 + tr;
    const int orow = (col < 1024) ? col
                   : (col < 2048) ? 1024 + 2 * (col - 1024)
                                  : 1024 + 2 * (col - 2048) + 1;
    f16x4 o;
    #pragma unroll
    for (int e = 0; e < 4; ++e) o[e] = (_Float16)tile[tc + e][tr];
    *(f16x4*)&out[(size_t)orow * 1024 + k0 + tc] = o;
}

// ---------------------------------------------------------------- row RMS helper
__device__ __forceinline__ float row_rms_scale(float ss) {
    #pragma unroll
    for (int off = 32; off > 0; off >>= 1) ss += __shfl_down(ss, off, 64);
    __shared__ float wsum[4];
    if ((threadIdx.x & 63) == 0) wsum[threadIdx.x >> 6] = ss;
    __syncthreads();
    const float nrm = sqrtf(wsum[0] + wsum[1] + wsum[2] + wsum[3]);
    return 32.0f / fmaxf(nrm, 1e-12f);
}

// ---------------------------------------------------------------- embed + rms
__global__ __launch_bounds__(256) void embed_rms_kernel(
    const int* __restrict__ tokens, const float* __restrict__ emb,
    const float* __restrict__ g, float* __restrict__ x, _Float16* __restrict__ xn)
{
    const int row = blockIdx.x;
    const int t = tokens[row];
    const int c = threadIdx.x * 4;
    fx4 v = *(const fx4*)&emb[(size_t)t * 1024 + c];
    *(fx4*)&x[(size_t)row * 1024 + c] = v;
    const float scale = row_rms_scale(v[0]*v[0] + v[1]*v[1] + v[2]*v[2] + v[3]*v[3]);
    fx4 gg = *(const fx4*)&g[c];
    f16x4 o;
    #pragma unroll
    for (int e = 0; e < 4; ++e) o[e] = (_Float16)(v[e] * scale * gg[e]);
    *(f16x4*)&xn[(size_t)row * 1024 + c] = o;
}

// ---------------------------------------------------------------- rms -> fp16
__global__ __launch_bounds__(256) void rms_f16_kernel(
    const float* __restrict__ x, const float* __restrict__ g,
    _Float16* __restrict__ outh)
{
    const int row = blockIdx.x;
    const int c = threadIdx.x * 4;
    fx4 v = *(const fx4*)&x[(size_t)row * 1024 + c];
    const float scale = row_rms_scale(v[0]*v[0] + v[1]*v[1] + v[2]*v[2] + v[3]*v[3]);
    fx4 gg = *(const fx4*)&g[c];
    f16x4 o;
    #pragma unroll
    for (int e = 0; e < 4; ++e) o[e] = (_Float16)(v[e] * scale * gg[e]);
    *(f16x4*)&outh[(size_t)row * 1024 + c] = o;
}

// ---------------------------------------------------------------- gate-loop scan
__device__ __forceinline__ int pidx(int i) { return i + (i >> 5); }

__global__ __launch_bounds__(256) void scanT_kernel(
    const float* __restrict__ kvT, const float* __restrict__ aReT,
    const float* __restrict__ aImT, const float* __restrict__ qT,
    float* __restrict__ yT)
{
    const int tid = threadIdx.x;
    const size_t base = (size_t)blockIdx.x * 2048;
    __shared__ float s_re[2048 + 64], s_im[2048 + 64], s_kv[2048 + 64];

    for (int i = tid; i < 512; i += 256) {
        fx4 kv = *(const fx4*)&kvT[base + i * 4];
        fx4 re = *(const fx4*)&aReT[base + i * 4];
        fx4 im = *(const fx4*)&aImT[base + i * 4];
        #pragma unroll
        for (int e = 0; e < 4; ++e) {
            const int j = pidx(i * 4 + e);
            s_kv[j] = kv[e]; s_re[j] = re[e]; s_im[j] = im[e];
        }
    }
    __syncthreads();

    for (int d = 0; d < 4; ++d) {
        const int half = 1 << d, stride = half << 1;
        const int npairs = 2048 >> (d + 1);
        for (int i = tid; i < npairs; i += 256) {
            const int rj = pidx(i * stride + stride - 1);
            const int lj = pidx(i * stride + stride - 1 - half);
            float lre = s_re[lj], lim = s_im[lj], lkv = s_kv[lj];
            float rre = s_re[rj], rim = s_im[rj], rkv = s_kv[rj];
            s_kv[rj] = rre * lkv + rkv;
            s_re[rj] = rre * lre - rim * lim;
            s_im[rj] = rre * lim + rim * lre;
        }
        __syncthreads();
    }
    if (tid < 64) {
        #pragma unroll
        for (int d = 4; d < 11; ++d) {
            const int half = 1 << d, stride = half << 1;
            const int npairs = 2048 >> (d + 1);
            if (tid < npairs) {
                const int rj = pidx(tid * stride + stride - 1);
                const int lj = pidx(tid * stride + stride - 1 - half);
                float lre = s_re[lj], lim = s_im[lj], lkv = s_kv[lj];
                float rre = s_re[rj], rim = s_im[rj], rkv = s_kv[rj];
                s_kv[rj] = rre * lkv + rkv;
                s_re[rj] = rre * lre - rim * lim;
                s_im[rj] = rre * lim + rim * lre;
            }
        }
        #pragma unroll
        for (int d = 9; d >= 4; --d) {
            const int w = 1 << d;
            const int nupd = (2048 >> (d + 1)) - 1;
            if (tid < nupd) {
                const int i = tid + 1;
                const int rj = pidx((2 * i + 1) * w - 1);
                const int lj = pidx(2 * i * w - 1);
                float lre = s_re[lj], lim = s_im[lj], lkv = s_kv[lj];
                float rre = s_re[rj], rim = s_im[rj], rkv = s_kv[rj];
                s_kv[rj] = rre * lkv + rkv;
                s_re[rj] = rre * lre - rim * lim;
                s_im[rj] = rre * lim + rim * lre;
            }
        }
    }
    __syncthreads();
    for (int d = 3; d >= 0; --d) {
        const int w = 1 << d;
        const int nupd = (2048 >> (d + 1)) - 1;
        for (int t = tid; t < nupd; t += 256) {
            const int i = t + 1;
            const int rj = pidx((2 * i + 1) * w - 1);
            const int lj = pidx(2 * i * w - 1);
            float lre = s_re[lj], lim = s_im[lj], lkv = s_kv[lj];
            float rre = s_re[rj], rim = s_im[rj], rkv = s_kv[rj];
            s_kv[rj] = rre * lkv + rkv;
            s_re[rj] = rre * lre - rim * lim;
            s_im[rj] = rre * lim + rim * lre;
        }
        __syncthreads();
    }
    for (int i = tid; i < 512; i += 256) {
        fx4 q = *(const fx4*)&qT[base + i * 4];
        fx4 o;
        #pragma unroll
        for (int e = 0; e < 4; ++e) o[e] = q[e] * s_kv[pidx(i * 4 + e)];
        *(fx4*)&yT[base + i * 4] = o;
    }
}

// ---------------------------------------------------------------- gating
__global__ __launch_bounds__(256) void gate_kernel(
    const _Float16* __restrict__ G, const float* __restrict__ yT,
    _Float16* __restrict__ gated)
{
    __shared__ float ty[32][33];
    const int n0 = blockIdx.x * 32, h0 = blockIdx.y * 32, b = blockIdx.z;
    const int tr = threadIdx.x >> 3;
    const int tc = (threadIdx.x & 7) * 4;
    fx4 yv = *(const fx4*)&yT[((size_t)b * 1024 + h0 + tr) * 2048 + n0 + tc];
    #pragma unroll
    for (int e = 0; e < 4; ++e) ty[tr][tc + e] = yv[e];
    __syncthreads();
    const size_t grow = ((size_t)b * 2048 + n0 + tr) * 1024 + h0 + tc;
    f16x4 gv = *(const f16x4*)&G[grow];
    f16x4 o;
    #pragma unroll
    for (int e = 0; e < 4; ++e) {
        const float g = (float)gv[e];
        const float s = g / (1.0f + expf(-g));   // silu
        o[e] = (_Float16)(s * ty[tc + e][tr]);
    }
    *(f16x4*)&gated[grow] = o;
}

// ---------------------------------------------------------------- W2 combine + next-layer RMS
__global__ __launch_bounds__(256) void combine2_rms_kernel(
    const float* __restrict__ p, const float* __restrict__ bias,
    const float* __restrict__ g, float* __restrict__ x, _Float16* __restrict__ xn)
{
    const int row = blockIdx.x;
    const int c = threadIdx.x * 4;
    const size_t i = (size_t)row * 1024 + c;
    fx4 a = *(const fx4*)&p[i];
    fx4 b = *(const fx4*)&p[i + (size_t)4096 * 1024];
    fx4 xx = *(const fx4*)&x[i];
    fx4 bb = *(const fx4*)&bias[c];
    fx4 o;
    #pragma unroll
    for (int e = 0; e < 4; ++e) o[e] = xx[e] + (a[e] + b[e] + bb[e]);
    *(fx4*)&x[i] = o;
    const float scale = row_rms_scale(o[0]*o[0] + o[1]*o[1] + o[2]*o[2] + o[3]*o[3]);
    fx4 gg = *(const fx4*)&g[c];
    f16x4 oh;
    #pragma unroll
    for (int e = 0; e < 4; ++e) oh[e] = (_Float16)(o[e] * scale * gg[e]);
    *(f16x4*)&xn[i] = oh;
}

// ---------------------------------------------------------------- GEMM (2-barrier, proven)
template<int EPI, int BM, int BN, int WTM>
__global__ __launch_bounds__((BM / WTM) * (BN / 64) * 64) void gemm_kernel(
    const _Float16* __restrict__ A, const _Float16* __restrict__ Bt,
    const float* __restrict__ bias,
    float* __restrict__ Cf, float* __restrict__ Cf2, float* __restrict__ Cf3,
    float* __restrict__ aRe, float* __restrict__ aIm,
    _Float16* __restrict__ Ch,
    int M, int N, int K, int Kld)
{
    constexpr int NW      = BN / 64;
    constexpr int THREADS = (BM / WTM) * NW * 64;
    constexpr int M_REP   = WTM / 16;
    __shared__ __align__(16) _Float16 As[BM * 64];
    __shared__ __align__(16) _Float16 Bs[BN * 64];
    const int tid  = threadIdx.x;
    const int lane = tid & 63;
    const int wave = tid >> 6;
    const int bm = blockIdx.x, bn = blockIdx.y;
    const int bz = blockIdx.z;
    const int wm = (wave / NW) * WTM;
    const int wn = (wave % NW) * 64;

    A  += (size_t)bz * K;
    Bt += (size_t)bz * K;
    if (EPI == 0) Cf += (size_t)bz * M * N;

    fx4 acc[M_REP][4] = {};

    const size_t aRow0 = (size_t)bm * BM;
    const size_t bRow0 = (size_t)bn * BN;

    for (int k0 = 0; k0 < K; k0 += 64) {
        constexpr int QA = BM * 8 / THREADS;
        #pragma unroll
        for (int q = 0; q < QA; ++q) {
            const int chunk = q * THREADS + tid;
            const int row = chunk >> 3;
            const int slot = chunk & 7;
            const int gs = slot ^ (row & 7);
            const size_t aoff = (aRow0 + row) * (size_t)Kld + k0 + gs * 8;
            __builtin_amdgcn_global_load_lds((const AS1 void*)(A + aoff),
                (AS3 void*)((char*)As + chunk * 16), 16, 0, 0);
        }
        constexpr int QB = BN * 8 / THREADS;
        #pragma unroll
        for (int q = 0; q < QB; ++q) {
            const int chunk = q * THREADS + tid;
            const int row = chunk >> 3;
            const int slot = chunk & 7;
            const int gs = slot ^ (row & 7);
            const size_t boff = (bRow0 + row) * (size_t)Kld + k0 + gs * 8;
            __builtin_amdgcn_global_load_lds((const AS1 void*)(Bt + boff),
                (AS3 void*)((char*)Bs + chunk * 16), 16, 0, 0);
        }
        __syncthreads();

        #pragma unroll
        for (int kk = 0; kk < 2; ++kk) {
            const int sw = ((kk * 4 + (lane >> 4)) ^ (lane & 7)) * 16;
            f16x8 af[M_REP], bf[4];
            #pragma unroll
            for (int i = 0; i < M_REP; ++i) {
                const int row = wm + i * 16 + (lane & 15);
                af[i] = *(const f16x8*)((const char*)As + row * 128 + sw);
            }
            #pragma unroll
            for (int j = 0; j < 4; ++j) {
                const int row = wn + j * 16 + (lane & 15);
                bf[j] = *(const f16x8*)((const char*)Bs + row * 128 + sw);
            }
            #pragma unroll
            for (int i = 0; i < M_REP; ++i)
                #pragma unroll
                for (int j = 0; j < 4; ++j)
                    acc[i][j] = __builtin_amdgcn_mfma_f32_16x16x32_f16(
                        af[i], bf[j], acc[i][j], 0, 0, 0);
        }
        __syncthreads();
    }

    const int col_l = lane & 15, row_l = (lane >> 4) * 4;
    #pragma unroll
    for (int i = 0; i < M_REP; ++i) {
        #pragma unroll
        for (int j = 0; j < 4; ++j) {
            if (EPI == 6) {
                const int col  = bn * BN + wn + j * 16 + col_l;
                const int row0 = bm * BM + wm + i * 16 + row_l;
                const int b = row0 >> 11;
                const int n = row0 & 2047;
                if (col < 1024) {
                    *(fx4*)&Cf[((size_t)b * 1024 + col) * 2048 + n] = acc[i][j];
                } else if (col < 3072) {
                    fx4 partner;
                    #pragma unroll
                    for (int e = 0; e < 4; ++e)
                        partner[e] = __shfl_xor(acc[i][j][e], 1, 64);
                    if ((col & 1) == 0) {
                        fx4 kv;
                        #pragma unroll
                        for (int e = 0; e < 4; ++e) kv[e] = acc[i][j][e] * partner[e];
                        const int hh = (col - 1024) >> 1;
                        *(fx4*)&Cf2[((size_t)b * 1024 + hh) * 2048 + n] = kv;
                    }
                } else if (col < 5120) {
                    fx4 my;
                    #pragma unroll
                    for (int e = 0; e < 4; ++e) my[e] = acc[i][j][e] + bias[col - 3072];
                    fx4 partner;
                    #pragma unroll
                    for (int e = 0; e < 4; ++e)
                        partner[e] = __shfl_xor(my[e], 1, 64);
                    const bool isRe = (col & 1) == 0;
                    const int hh = (col - 3072) >> 1;
                    fx4 o;
                    #pragma unroll
                    for (int e = 0; e < 4; ++e) {
                        const float re = isRe ? my[e] : partner[e];
                        const float im = isRe ? partner[e] : my[e];
                        const float r = sqrtf(re * re + im * im);
                        const float sg = 1.0f / (1.0f + expf(-r));
                        float a_re, a_im;
                        if (r > 0.0f) { const float inv = sg / r; a_re = re * inv; a_im = im * inv; }
                        else          { a_re = sg; a_im = 0.0f; }
                        o[e] = isRe ? a_re : a_im;
                    }
                    if (isRe) *(fx4*)&aRe[((size_t)b * 1024 + hh) * 2048 + n] = o;
                    else      *(fx4*)&aIm[((size_t)b * 1024 + hh) * 2048 + n] = o;
                } else {
                    #pragma unroll
                    for (int r = 0; r < 4; ++r)
                        Ch[(size_t)(row0 + r) * 1024 + (col - 5120)] = (_Float16)acc[i][j][r];
                }
            } else {
                #pragma unroll
                for (int r = 0; r < 4; ++r) {
                    const int row = bm * BM + wm + i * 16 + row_l + r;
                    const int col = bn * BN + wn + j * 16 + col_l;
                    const float v = acc[i][j][r];
                    if (EPI == 0) {
                        Cf[(size_t)row * N + col] = v;
                    } else if (EPI == 2) {
                        Cf[(size_t)row * N + col] += v;
                    } else if (EPI == 4) {
                        const float t = v + bias[col];
                        const float gelu = 0.5f * t * (1.0f + erff(t * 0.70710678118654752f));
                        Ch[(size_t)row * N + col] = (_Float16)gelu;
                    }
                }
            }
        }
    }
}

// ---------------------------------------------------------------- GEMM (ring-3 full-BK, logits)
// Identical body to the proven kernel except: 3-slot ring of full K-steps
// (A[256][64] 32KB + B[128][64] 16KB = 48KB/slot, 144KB, 1 block/CU) and
// COUNTED vmcnt(6) (2 K-steps in flight) + raw s_barrier instead of the
// implicit vmcnt(0) drain.  Phase t: stage(t+2) | ds_read/MFMA on slot t%3 |
// vmcnt(6) [retires stage(t+1), issued 2 phases (~2400cyc) earlier] | barrier.
// Slot (t+2)%3 was last read at phase t-1 (reads retired before its barrier).
// Epilogue: vmcnt(0) once at t==nT-2.  Bitwise-identical K order.
__global__ __launch_bounds__(512) void gemm_ring3b_kernel(
    const _Float16* __restrict__ A, const _Float16* __restrict__ Bt,
    float* __restrict__ Cf, int M, int N, int K)
{
    __shared__ __align__(16) _Float16 As[3][256 * 64];   // 96 KB
    __shared__ __align__(16) _Float16 Bs[3][128 * 64];   // 48 KB
    const int tid = threadIdx.x, lane = tid & 63, wave = tid >> 6;
    const int bm = blockIdx.x, bn = blockIdx.y;
    const int wm = (wave >> 1) * 64, wn = (wave & 1) * 64;
    const size_t aRow0 = (size_t)bm * 256, bRow0 = (size_t)bn * 128;

    fx4 acc[4][4] = {};

    auto stage = [&](int t) {
        const int s = t % 3;
        const int k0 = t * 64;
        #pragma unroll
        for (int q = 0; q < 4; ++q) {              // A: 2048 chunks, 4/thread
            const int chunk = q * 512 + tid;
            const int row = chunk >> 3;
            const int gs = (chunk & 7) ^ (row & 7);
            const size_t off = (aRow0 + row) * (size_t)K + k0 + gs * 8;
            __builtin_amdgcn_global_load_lds((const AS1 void*)(A + off),
                (AS3 void*)((char*)&As[s][0] + chunk * 16), 16, 0, 0);
        }
        #pragma unroll
        for (int q = 0; q < 2; ++q) {              // B: 1024 chunks, 2/thread
            const int chunk = q * 512 + tid;
            const int row = chunk >> 3;
            const int gs = (chunk & 7) ^ (row & 7);
            const size_t off = (bRow0 + row) * (size_t)K + k0 + gs * 8;
            __builtin_amdgcn_global_load_lds((const AS1 void*)(Bt + off),
                (AS3 void*)((char*)&Bs[s][0] + chunk * 16), 16, 0, 0);
        }
    };

    const int nT = K >> 6;                         // 16
    stage(0); stage(1);
    asm volatile("s_waitcnt vmcnt(6)" ::: "memory");   // t=0 landed
    __builtin_amdgcn_s_barrier();

    for (int t = 0; t < nT; ++t) {
        const int s = t % 3;
        if (t + 2 < nT) stage(t + 2);
        #pragma unroll
        for (int kk = 0; kk < 2; ++kk) {
            const int sw = ((kk * 4 + (lane >> 4)) ^ (lane & 7)) * 16;
            f16x8 af[4], bf[4];
            #pragma unroll
            for (int i = 0; i < 4; ++i) {
                const int row = wm + i * 16 + (lane & 15);
                af[i] = *(const f16x8*)((const char*)&As[s][0] + row * 128 + sw);
            }
            #pragma unroll
            for (int j = 0; j < 4; ++j) {
                const int row = wn + j * 16 + (lane & 15);
                bf[j] = *(const f16x8*)((const char*)&Bs[s][0] + row * 128 + sw);
            }
            __builtin_amdgcn_s_setprio(1);
            #pragma unroll
            for (int i = 0; i < 4; ++i)
                #pragma unroll
                for (int j = 0; j < 4; ++j)
                    acc[i][j] = __builtin_amdgcn_mfma_f32_16x16x32_f16(
                        af[i], bf[j], acc[i][j], 0, 0, 0);
            __builtin_amdgcn_s_setprio(0);
        }
        if (t + 2 < nT)      asm volatile("s_waitcnt vmcnt(6)" ::: "memory");
        else if (t + 1 < nT) asm volatile("s_waitcnt vmcnt(0)" ::: "memory");
        __builtin_amdgcn_s_barrier();
    }

    const int col_l = lane & 15, row_l = (lane >> 4) * 4;
    #pragma unroll
    for (int i = 0; i < 4; ++i)
        #pragma unroll
        for (int j = 0; j < 4; ++j)
            #pragma unroll
            for (int r = 0; r < 4; ++r) {
                const int row = bm * 256 + wm + i * 16 + row_l + r;
                const int col = bn * 128 + wn + j * 16 + col_l;
                Cf[(size_t)row * N + col] = acc[i][j][r];
            }
}

// ---------------------------------------------------------------- host
extern "C" void kernel_launch(void* const* d_in, const int* in_sizes, int n_in,
                              void* d_out, int out_size, void* d_ws, size_t ws_size,
                              hipStream_t stream)
{
    const int*   tokens = (const int*)d_in[0];
    const float* emb  = (const float*)d_in[1];
    const float* g1   = (const float*)d_in[2];
    const float* Wqkv = (const float*)d_in[3];
    const float* Wa   = (const float*)d_in[4];
    const float* ba   = (const float*)d_in[5];
    const float* Wg   = (const float*)d_in[6];
    const float* Wo   = (const float*)d_in[7];
    const float* g2   = (const float*)d_in[8];
    const float* W1   = (const float*)d_in[9];
    const float* b1   = (const float*)d_in[10];
    const float* W2   = (const float*)d_in[11];
    const float* b2   = (const float*)d_in[12];
    const float* gf   = (const float*)d_in[13];
    const float* Wl   = (const float*)d_in[14];
    float* out = (float*)d_out;

    char* ws = (char*)d_ws;
    size_t off = 0;
    auto take = [&](size_t bytes) {
        char* p = ws + off; off += (bytes + 255) & ~(size_t)255; return p;
    };

    _Float16* wcat = (_Float16*)take((size_t)4 * 6144 * 1024 * 2);
    _Float16* wo   = (_Float16*)take((size_t)4 * 1024 * 1024 * 2);
    _Float16* w1   = (_Float16*)take((size_t)4 * 4096 * 1024 * 2);
    _Float16* w2   = (_Float16*)take((size_t)4 * 1024 * 4096 * 2);
    char*     wlRegion = take((size_t)64 << 20);
    _Float16* wl   = (_Float16*)wlRegion;
    float*    x    = (float*)take((size_t)4096 * 1024 * 4);
    _Float16* xn   = (_Float16*)take((size_t)4096 * 1024 * 2);
    float*    qkvb = (float*)take((size_t)4096 * 3072 * 4);
    float*    alb  = (float*)take((size_t)4096 * 2048 * 4);
    _Float16* G    = (_Float16*)take((size_t)4096 * 1024 * 2);

    float* qT   = (float*)wlRegion;
    float* kvT  = (float*)(wlRegion + ((size_t)16 << 20));
    float* aReT = (float*)(wlRegion + ((size_t)32 << 20));
    float* aImT = (float*)(wlRegion + ((size_t)48 << 20));
    float*    yT    = alb;
    _Float16* gated = (_Float16*)((char*)alb + ((size_t)16 << 20));
    _Float16* h     = (_Float16*)qkvb;
    float*    part  = alb;

    const dim3 blk(256);

    transpose_qkv_kernel<<<dim3(32, 96, 4), blk, 0, stream>>>(Wqkv, wcat);
    transpose_f16_kernel<<<dim3(32,  64, 4), blk, 0, stream>>>(Wa,   wcat + 3072 * 1024, 1024, 2048, (size_t)6144 * 1024);
    transpose_f16_kernel<<<dim3(32,  32, 4), blk, 0, stream>>>(Wg,   wcat + 5120 * 1024, 1024, 1024, (size_t)6144 * 1024);
    transpose_f16_kernel<<<dim3(32,  32, 4), blk, 0, stream>>>(Wo,   wo,  1024, 1024, (size_t)1024 * 1024);
    transpose_f16_kernel<<<dim3(32, 128, 4), blk, 0, stream>>>(W1,   w1,  1024, 4096, (size_t)4096 * 1024);
    transpose_f16_kernel<<<dim3(128, 32, 4), blk, 0, stream>>>(W2,   w2,  4096, 1024, (size_t)1024 * 4096);

    embed_rms_kernel<<<4096, blk, 0, stream>>>(tokens, emb, g1, x, xn);

    for (int i = 0; i < 4; ++i) {
        gemm_kernel<6, 256, 128, 64><<<dim3(16, 48), dim3(512), 0, stream>>>(
            xn, wcat + (size_t)i * 6144 * 1024, ba + i * 2048,
            qT, kvT, nullptr, aReT, aImT, G, 4096, 6144, 1024, 1024);
        scanT_kernel<<<2048, blk, 0, stream>>>(kvT, aReT, aImT, qT, yT);
        gate_kernel<<<dim3(64, 32, 2), blk, 0, stream>>>(G, yT, gated);
        gemm_kernel<2, 128, 128, 64><<<dim3(32, 8), blk, 0, stream>>>(
            gated, wo + (size_t)i * 1024 * 1024, nullptr,
            x, nullptr, nullptr, nullptr, nullptr, nullptr, 4096, 1024, 1024, 1024);
        rms_f16_kernel<<<4096, blk, 0, stream>>>(x, g2 + i * 1024, xn);
        gemm_kernel<4, 256, 128, 64><<<dim3(16, 32), dim3(512), 0, stream>>>(
            xn, w1 + (size_t)i * 4096 * 1024, b1 + i * 4096,
            nullptr, nullptr, nullptr, nullptr, nullptr, h, 4096, 4096, 1024, 1024);
        gemm_kernel<0, 256, 128, 64><<<dim3(16, 8, 2), dim3(512), 0, stream>>>(
            h, w2 + (size_t)i * 1024 * 4096, nullptr,
            part, nullptr, nullptr, nullptr, nullptr, nullptr, 4096, 1024, 2048, 4096);
        const float* gnext = (i < 3) ? (g1 + (i + 1) * 1024) : gf;
        combine2_rms_kernel<<<4096, blk, 0, stream>>>(part, b2 + i * 1024, gnext, x, xn);
    }

    transpose_f16_kernel<<<dim3(32, 1000, 1), blk, 0, stream>>>(Wl, wl, 1024, 32000, 0);

    // logits: ring-3 full-BK counted-vmcnt pipeline
    gemm_ring3b_kernel<<<dim3(16, 250), dim3(512), 0, stream>>>(
        xn, wl, out, 4096, 32000, 1024);
}

// Round 17
// 1537.092 us; speedup vs baseline: 1.1129x; 1.1129x over previous
//
#include <hip/hip_runtime.h>

// ---------------------------------------------------------------------------
// Transformer (GateLoop-style) forward, MI355X/gfx950.  Round 17 (final).
//  = round 15 (best: 1546us) with logits reverted to the proven 2-barrier
//    kernel, + W2 split-K partials stored fp16 (saves 32MiB/layer HBM).
//  Occupancy lesson banked from r12/r13/r16: 2-barrier 48KB/3-blocks-per-CU
//  beats every counted-vmcnt pipeline at K=1024 (490/411/336 vs 315us).
// ---------------------------------------------------------------------------

typedef float fx4 __attribute__((ext_vector_type(4)));
typedef _Float16 f16x8 __attribute__((ext_vector_type(8)));
typedef _Float16 f16x4 __attribute__((ext_vector_type(4)));

#define AS1 __attribute__((address_space(1)))
#define AS3 __attribute__((address_space(3)))

// ---------------------------------------------------------------- transpose
__global__ __launch_bounds__(256) void transpose_f16_kernel(
    const float* __restrict__ in, _Float16* __restrict__ out,
    int K, int N, size_t ostride)
{
    __shared__ float tile[32][33];
    const int b = blockIdx.z;
    in  += (size_t)b * K * N;
    out += (size_t)b * ostride;
    const int k0 = blockIdx.x * 32, n0 = blockIdx.y * 32;
    const int tr = threadIdx.x >> 3;
    const int tc = (threadIdx.x & 7) * 4;
    fx4 v = *(const fx4*)&in[(size_t)(k0 + tr) * N + n0 + tc];
    tile[tr][tc + 0] = v[0]; tile[tr][tc + 1] = v[1];
    tile[tr][tc + 2] = v[2]; tile[tr][tc + 3] = v[3];
    __syncthreads();
    f16x4 o;
    #pragma unroll
    for (int e = 0; e < 4; ++e) o[e] = (_Float16)tile[tc + e][tr];
    *(f16x4*)&out[(size_t)(n0 + tr) * K + k0 + tc] = o;
}

// Wqkv transpose with k/v interleave
__global__ __launch_bounds__(256) void transpose_qkv_kernel(
    const float* __restrict__ in, _Float16* __restrict__ out)
{
    __shared__ float tile[32][33];
    const int b = blockIdx.z;
    in  += (size_t)b * 1024 * 3072;
    out += (size_t)b * 6144 * 1024;
    const int k0 = blockIdx.x * 32, n0 = blockIdx.y * 32;
    const int tr = threadIdx.x >> 3;
    const int tc = (threadIdx.x & 7) * 4;
    fx4 v = *(const fx4*)&in[(size_t)(k0 + tr) * 3072 + n0 + tc];
    tile[tr][tc + 0] = v[0]; tile[tr][tc + 1] = v[1];
    tile[tr][tc + 2] = v[2]; tile[tr][tc + 3] = v[3];
    __syncthreads();
    const int col = n0 + tr;
    const int orow = (col < 1024) ? col
                   : (col < 2048) ? 1024 + 2 * (col - 1024)
                                  : 1024 + 2 * (col - 2048) + 1;
    f16x4 o;
    #pragma unroll
    for (int e = 0; e < 4; ++e) o[e] = (_Float16)tile[tc + e][tr];
    *(f16x4*)&out[(size_t)orow * 1024 + k0 + tc] = o;
}

// ---------------------------------------------------------------- row RMS helper
__device__ __forceinline__ float row_rms_scale(float ss) {
    #pragma unroll
    for (int off = 32; off > 0; off >>= 1) ss += __shfl_down(ss, off, 64);
    __shared__ float wsum[4];
    if ((threadIdx.x & 63) == 0) wsum[threadIdx.x >> 6] = ss;
    __syncthreads();
    const float nrm = sqrtf(wsum[0] + wsum[1] + wsum[2] + wsum[3]);
    return 32.0f / fmaxf(nrm, 1e-12f);
}

// ---------------------------------------------------------------- embed + rms
__global__ __launch_bounds__(256) void embed_rms_kernel(
    const int* __restrict__ tokens, const float* __restrict__ emb,
    const float* __restrict__ g, float* __restrict__ x, _Float16* __restrict__ xn)
{
    const int row = blockIdx.x;
    const int t = tokens[row];
    const int c = threadIdx.x * 4;
    fx4 v = *(const fx4*)&emb[(size_t)t * 1024 + c];
    *(fx4*)&x[(size_t)row * 1024 + c] = v;
    const float scale = row_rms_scale(v[0]*v[0] + v[1]*v[1] + v[2]*v[2] + v[3]*v[3]);
    fx4 gg = *(const fx4*)&g[c];
    f16x4 o;
    #pragma unroll
    for (int e = 0; e < 4; ++e) o[e] = (_Float16)(v[e] * scale * gg[e]);
    *(f16x4*)&xn[(size_t)row * 1024 + c] = o;
}

// ---------------------------------------------------------------- rms -> fp16
__global__ __launch_bounds__(256) void rms_f16_kernel(
    const float* __restrict__ x, const float* __restrict__ g,
    _Float16* __restrict__ outh)
{
    const int row = blockIdx.x;
    const int c = threadIdx.x * 4;
    fx4 v = *(const fx4*)&x[(size_t)row * 1024 + c];
    const float scale = row_rms_scale(v[0]*v[0] + v[1]*v[1] + v[2]*v[2] + v[3]*v[3]);
    fx4 gg = *(const fx4*)&g[c];
    f16x4 o;
    #pragma unroll
    for (int e = 0; e < 4; ++e) o[e] = (_Float16)(v[e] * scale * gg[e]);
    *(f16x4*)&outh[(size_t)row * 1024 + c] = o;
}

// ---------------------------------------------------------------- gate-loop scan
__device__ __forceinline__ int pidx(int i) { return i + (i >> 5); }

__global__ __launch_bounds__(256) void scanT_kernel(
    const float* __restrict__ kvT, const float* __restrict__ aReT,
    const float* __restrict__ aImT, const float* __restrict__ qT,
    float* __restrict__ yT)
{
    const int tid = threadIdx.x;
    const size_t base = (size_t)blockIdx.x * 2048;
    __shared__ float s_re[2048 + 64], s_im[2048 + 64], s_kv[2048 + 64];

    for (int i = tid; i < 512; i += 256) {
        fx4 kv = *(const fx4*)&kvT[base + i * 4];
        fx4 re = *(const fx4*)&aReT[base + i * 4];
        fx4 im = *(const fx4*)&aImT[base + i * 4];
        #pragma unroll
        for (int e = 0; e < 4; ++e) {
            const int j = pidx(i * 4 + e);
            s_kv[j] = kv[e]; s_re[j] = re[e]; s_im[j] = im[e];
        }
    }
    __syncthreads();

    for (int d = 0; d < 4; ++d) {
        const int half = 1 << d, stride = half << 1;
        const int npairs = 2048 >> (d + 1);
        for (int i = tid; i < npairs; i += 256) {
            const int rj = pidx(i * stride + stride - 1);
            const int lj = pidx(i * stride + stride - 1 - half);
            float lre = s_re[lj], lim = s_im[lj], lkv = s_kv[lj];
            float rre = s_re[rj], rim = s_im[rj], rkv = s_kv[rj];
            s_kv[rj] = rre * lkv + rkv;
            s_re[rj] = rre * lre - rim * lim;
            s_im[rj] = rre * lim + rim * lre;
        }
        __syncthreads();
    }
    if (tid < 64) {
        #pragma unroll
        for (int d = 4; d < 11; ++d) {
            const int half = 1 << d, stride = half << 1;
            const int npairs = 2048 >> (d + 1);
            if (tid < npairs) {
                const int rj = pidx(tid * stride + stride - 1);
                const int lj = pidx(tid * stride + stride - 1 - half);
                float lre = s_re[lj], lim = s_im[lj], lkv = s_kv[lj];
                float rre = s_re[rj], rim = s_im[rj], rkv = s_kv[rj];
                s_kv[rj] = rre * lkv + rkv;
                s_re[rj] = rre * lre - rim * lim;
                s_im[rj] = rre * lim + rim * lre;
            }
        }
        #pragma unroll
        for (int d = 9; d >= 4; --d) {
            const int w = 1 << d;
            const int nupd = (2048 >> (d + 1)) - 1;
            if (tid < nupd) {
                const int i = tid + 1;
                const int rj = pidx((2 * i + 1) * w - 1);
                const int lj = pidx(2 * i * w - 1);
                float lre = s_re[lj], lim = s_im[lj], lkv = s_kv[lj];
                float rre = s_re[rj], rim = s_im[rj], rkv = s_kv[rj];
                s_kv[rj] = rre * lkv + rkv;
                s_re[rj] = rre * lre - rim * lim;
                s_im[rj] = rre * lim + rim * lre;
            }
        }
    }
    __syncthreads();
    for (int d = 3; d >= 0; --d) {
        const int w = 1 << d;
        const int nupd = (2048 >> (d + 1)) - 1;
        for (int t = tid; t < nupd; t += 256) {
            const int i = t + 1;
            const int rj = pidx((2 * i + 1) * w - 1);
            const int lj = pidx(2 * i * w - 1);
            float lre = s_re[lj], lim = s_im[lj], lkv = s_kv[lj];
            float rre = s_re[rj], rim = s_im[rj], rkv = s_kv[rj];
            s_kv[rj] = rre * lkv + rkv;
            s_re[rj] = rre * lre - rim * lim;
            s_im[rj] = rre * lim + rim * lre;
        }
        __syncthreads();
    }
    for (int i = tid; i < 512; i += 256) {
        fx4 q = *(const fx4*)&qT[base + i * 4];
        fx4 o;
        #pragma unroll
        for (int e = 0; e < 4; ++e) o[e] = q[e] * s_kv[pidx(i * 4 + e)];
        *(fx4*)&yT[base + i * 4] = o;
    }
}

// ---------------------------------------------------------------- gating
__global__ __launch_bounds__(256) void gate_kernel(
    const _Float16* __restrict__ G, const float* __restrict__ yT,
    _Float16* __restrict__ gated)
{
    __shared__ float ty[32][33];
    const int n0 = blockIdx.x * 32, h0 = blockIdx.y * 32, b = blockIdx.z;
    const int tr = threadIdx.x >> 3;
    const int tc = (threadIdx.x & 7) * 4;
    fx4 yv = *(const fx4*)&yT[((size_t)b * 1024 + h0 + tr) * 2048 + n0 + tc];
    #pragma unroll
    for (int e = 0; e < 4; ++e) ty[tr][tc + e] = yv[e];
    __syncthreads();
    const size_t grow = ((size_t)b * 2048 + n0 + tr) * 1024 + h0 + tc;
    f16x4 gv = *(const f16x4*)&G[grow];
    f16x4 o;
    #pragma unroll
    for (int e = 0; e < 4; ++e) {
        const float g = (float)gv[e];
        const float s = g / (1.0f + expf(-g));   // silu
        o[e] = (_Float16)(s * ty[tc + e][tr]);
    }
    *(f16x4*)&gated[grow] = o;
}

// ---------------------------------------------------------------- W2 combine + next-layer RMS
// partials fp16; x += p0 + p1 + bias; xn = fp16(rms(x) * g)
__global__ __launch_bounds__(256) void combine2_rms_kernel(
    const _Float16* __restrict__ p, const float* __restrict__ bias,
    const float* __restrict__ g, float* __restrict__ x, _Float16* __restrict__ xn)
{
    const int row = blockIdx.x;
    const int c = threadIdx.x * 4;
    const size_t i = (size_t)row * 1024 + c;
    f16x4 a = *(const f16x4*)&p[i];
    f16x4 b = *(const f16x4*)&p[i + (size_t)4096 * 1024];
    fx4 xx = *(const fx4*)&x[i];
    fx4 bb = *(const fx4*)&bias[c];
    fx4 o;
    #pragma unroll
    for (int e = 0; e < 4; ++e) o[e] = xx[e] + ((float)a[e] + (float)b[e] + bb[e]);
    *(fx4*)&x[i] = o;
    const float scale = row_rms_scale(o[0]*o[0] + o[1]*o[1] + o[2]*o[2] + o[3]*o[3]);
    fx4 gg = *(const fx4*)&g[c];
    f16x4 oh;
    #pragma unroll
    for (int e = 0; e < 4; ++e) oh[e] = (_Float16)(o[e] * scale * gg[e]);
    *(f16x4*)&xn[i] = oh;
}

// ---------------------------------------------------------------- GEMM (2-barrier, proven)
// EPI: 0=store f32 (+bz*M*N), 2=Cf+=v, 4=Ch=f16(gelu(v+bias)),
//      6=fused scan-prep routing, 7=Ch=f16(v) (+bz*M*N, split-K partials)
template<int EPI, int BM, int BN, int WTM>
__global__ __launch_bounds__((BM / WTM) * (BN / 64) * 64) void gemm_kernel(
    const _Float16* __restrict__ A, const _Float16* __restrict__ Bt,
    const float* __restrict__ bias,
    float* __restrict__ Cf, float* __restrict__ Cf2, float* __restrict__ Cf3,
    float* __restrict__ aRe, float* __restrict__ aIm,
    _Float16* __restrict__ Ch,
    int M, int N, int K, int Kld)
{
    constexpr int NW      = BN / 64;
    constexpr int THREADS = (BM / WTM) * NW * 64;
    constexpr int M_REP   = WTM / 16;
    __shared__ __align__(16) _Float16 As[BM * 64];
    __shared__ __align__(16) _Float16 Bs[BN * 64];
    const int tid  = threadIdx.x;
    const int lane = tid & 63;
    const int wave = tid >> 6;
    const int bm = blockIdx.x, bn = blockIdx.y;
    const int bz = blockIdx.z;
    const int wm = (wave / NW) * WTM;
    const int wn = (wave % NW) * 64;

    A  += (size_t)bz * K;
    Bt += (size_t)bz * K;
    if (EPI == 0) Cf += (size_t)bz * M * N;
    if (EPI == 7) Ch += (size_t)bz * M * N;

    fx4 acc[M_REP][4] = {};

    const size_t aRow0 = (size_t)bm * BM;
    const size_t bRow0 = (size_t)bn * BN;

    for (int k0 = 0; k0 < K; k0 += 64) {
        constexpr int QA = BM * 8 / THREADS;
        #pragma unroll
        for (int q = 0; q < QA; ++q) {
            const int chunk = q * THREADS + tid;
            const int row = chunk >> 3;
            const int slot = chunk & 7;
            const int gs = slot ^ (row & 7);
            const size_t aoff = (aRow0 + row) * (size_t)Kld + k0 + gs * 8;
            __builtin_amdgcn_global_load_lds((const AS1 void*)(A + aoff),
                (AS3 void*)((char*)As + chunk * 16), 16, 0, 0);
        }
        constexpr int QB = BN * 8 / THREADS;
        #pragma unroll
        for (int q = 0; q < QB; ++q) {
            const int chunk = q * THREADS + tid;
            const int row = chunk >> 3;
            const int slot = chunk & 7;
            const int gs = slot ^ (row & 7);
            const size_t boff = (bRow0 + row) * (size_t)Kld + k0 + gs * 8;
            __builtin_amdgcn_global_load_lds((const AS1 void*)(Bt + boff),
                (AS3 void*)((char*)Bs + chunk * 16), 16, 0, 0);
        }
        __syncthreads();

        #pragma unroll
        for (int kk = 0; kk < 2; ++kk) {
            const int sw = ((kk * 4 + (lane >> 4)) ^ (lane & 7)) * 16;
            f16x8 af[M_REP], bf[4];
            #pragma unroll
            for (int i = 0; i < M_REP; ++i) {
                const int row = wm + i * 16 + (lane & 15);
                af[i] = *(const f16x8*)((const char*)As + row * 128 + sw);
            }
            #pragma unroll
            for (int j = 0; j < 4; ++j) {
                const int row = wn + j * 16 + (lane & 15);
                bf[j] = *(const f16x8*)((const char*)Bs + row * 128 + sw);
            }
            #pragma unroll
            for (int i = 0; i < M_REP; ++i)
                #pragma unroll
                for (int j = 0; j < 4; ++j)
                    acc[i][j] = __builtin_amdgcn_mfma_f32_16x16x32_f16(
                        af[i], bf[j], acc[i][j], 0, 0, 0);
        }
        __syncthreads();
    }

    const int col_l = lane & 15, row_l = (lane >> 4) * 4;
    #pragma unroll
    for (int i = 0; i < M_REP; ++i) {
        #pragma unroll
        for (int j = 0; j < 4; ++j) {
            if (EPI == 6) {
                const int col  = bn * BN + wn + j * 16 + col_l;
                const int row0 = bm * BM + wm + i * 16 + row_l;
                const int b = row0 >> 11;
                const int n = row0 & 2047;
                if (col < 1024) {
                    *(fx4*)&Cf[((size_t)b * 1024 + col) * 2048 + n] = acc[i][j];
                } else if (col < 3072) {
                    fx4 partner;
                    #pragma unroll
                    for (int e = 0; e < 4; ++e)
                        partner[e] = __shfl_xor(acc[i][j][e], 1, 64);
                    if ((col & 1) == 0) {
                        fx4 kv;
                        #pragma unroll
                        for (int e = 0; e < 4; ++e) kv[e] = acc[i][j][e] * partner[e];
                        const int hh = (col - 1024) >> 1;
                        *(fx4*)&Cf2[((size_t)b * 1024 + hh) * 2048 + n] = kv;
                    }
                } else if (col < 5120) {
                    fx4 my;
                    #pragma unroll
                    for (int e = 0; e < 4; ++e) my[e] = acc[i][j][e] + bias[col - 3072];
                    fx4 partner;
                    #pragma unroll
                    for (int e = 0; e < 4; ++e)
                        partner[e] = __shfl_xor(my[e], 1, 64);
                    const bool isRe = (col & 1) == 0;
                    const int hh = (col - 3072) >> 1;
                    fx4 o;
                    #pragma unroll
                    for (int e = 0; e < 4; ++e) {
                        const float re = isRe ? my[e] : partner[e];
                        const float im = isRe ? partner[e] : my[e];
                        const float r = sqrtf(re * re + im * im);
                        const float sg = 1.0f / (1.0f + expf(-r));
                        float a_re, a_im;
                        if (r > 0.0f) { const float inv = sg / r; a_re = re * inv; a_im = im * inv; }
                        else          { a_re = sg; a_im = 0.0f; }
                        o[e] = isRe ? a_re : a_im;
                    }
                    if (isRe) *(fx4*)&aRe[((size_t)b * 1024 + hh) * 2048 + n] = o;
                    else      *(fx4*)&aIm[((size_t)b * 1024 + hh) * 2048 + n] = o;
                } else {
                    #pragma unroll
                    for (int r = 0; r < 4; ++r)
                        Ch[(size_t)(row0 + r) * 1024 + (col - 5120)] = (_Float16)acc[i][j][r];
                }
            } else {
                #pragma unroll
                for (int r = 0; r < 4; ++r) {
                    const int row = bm * BM + wm + i * 16 + row_l + r;
                    const int col = bn * BN + wn + j * 16 + col_l;
                    const float v = acc[i][j][r];
                    if (EPI == 0) {
                        Cf[(size_t)row * N + col] = v;
                    } else if (EPI == 2) {
                        Cf[(size_t)row * N + col] += v;
                    } else if (EPI == 4) {
                        const float t = v + bias[col];
                        const float gelu = 0.5f * t * (1.0f + erff(t * 0.70710678118654752f));
                        Ch[(size_t)row * N + col] = (_Float16)gelu;
                    } else if (EPI == 7) {
                        Ch[(size_t)row * N + col] = (_Float16)v;
                    }
                }
            }
        }
    }
}

// ---------------------------------------------------------------- host
extern "C" void kernel_launch(void* const* d_in, const int* in_sizes, int n_in,
                              void* d_out, int out_size, void* d_ws, size_t ws_size,
                              hipStream_t stream)
{
    const int*   tokens = (const int*)d_in[0];
    const float* emb  = (const float*)d_in[1];
    const float* g1   = (const float*)d_in[2];
    const float* Wqkv = (const float*)d_in[3];
    const float* Wa   = (const float*)d_in[4];
    const float* ba   = (const float*)d_in[5];
    const float* Wg   = (const float*)d_in[6];
    const float* Wo   = (const float*)d_in[7];
    const float* g2   = (const float*)d_in[8];
    const float* W1   = (const float*)d_in[9];
    const float* b1   = (const float*)d_in[10];
    const float* W2   = (const float*)d_in[11];
    const float* b2   = (const float*)d_in[12];
    const float* gf   = (const float*)d_in[13];
    const float* Wl   = (const float*)d_in[14];
    float* out = (float*)d_out;

    char* ws = (char*)d_ws;
    size_t off = 0;
    auto take = [&](size_t bytes) {
        char* p = ws + off; off += (bytes + 255) & ~(size_t)255; return p;
    };

    _Float16* wcat = (_Float16*)take((size_t)4 * 6144 * 1024 * 2);
    _Float16* wo   = (_Float16*)take((size_t)4 * 1024 * 1024 * 2);
    _Float16* w1   = (_Float16*)take((size_t)4 * 4096 * 1024 * 2);
    _Float16* w2   = (_Float16*)take((size_t)4 * 1024 * 4096 * 2);
    char*     wlRegion = take((size_t)64 << 20);
    _Float16* wl   = (_Float16*)wlRegion;
    float*    x    = (float*)take((size_t)4096 * 1024 * 4);
    _Float16* xn   = (_Float16*)take((size_t)4096 * 1024 * 2);
    float*    qkvb = (float*)take((size_t)4096 * 3072 * 4);
    float*    alb  = (float*)take((size_t)4096 * 2048 * 4);
    _Float16* G    = (_Float16*)take((size_t)4096 * 1024 * 2);

    float* qT   = (float*)wlRegion;
    float* kvT  = (float*)(wlRegion + ((size_t)16 << 20));
    float* aReT = (float*)(wlRegion + ((size_t)32 << 20));
    float* aImT = (float*)(wlRegion + ((size_t)48 << 20));
    float*    yT    = alb;
    _Float16* gated = (_Float16*)((char*)alb + ((size_t)16 << 20));
    _Float16* h     = (_Float16*)qkvb;
    _Float16* part  = (_Float16*)alb;   // fp16 partials: 2 x 8MiB

    const dim3 blk(256);

    transpose_qkv_kernel<<<dim3(32, 96, 4), blk, 0, stream>>>(Wqkv, wcat);
    transpose_f16_kernel<<<dim3(32,  64, 4), blk, 0, stream>>>(Wa,   wcat + 3072 * 1024, 1024, 2048, (size_t)6144 * 1024);
    transpose_f16_kernel<<<dim3(32,  32, 4), blk, 0, stream>>>(Wg,   wcat + 5120 * 1024, 1024, 1024, (size_t)6144 * 1024);
    transpose_f16_kernel<<<dim3(32,  32, 4), blk, 0, stream>>>(Wo,   wo,  1024, 1024, (size_t)1024 * 1024);
    transpose_f16_kernel<<<dim3(32, 128, 4), blk, 0, stream>>>(W1,   w1,  1024, 4096, (size_t)4096 * 1024);
    transpose_f16_kernel<<<dim3(128, 32, 4), blk, 0, stream>>>(W2,   w2,  4096, 1024, (size_t)1024 * 4096);

    embed_rms_kernel<<<4096, blk, 0, stream>>>(tokens, emb, g1, x, xn);

    for (int i = 0; i < 4; ++i) {
        gemm_kernel<6, 256, 128, 64><<<dim3(16, 48), dim3(512), 0, stream>>>(
            xn, wcat + (size_t)i * 6144 * 1024, ba + i * 2048,
            qT, kvT, nullptr, aReT, aImT, G, 4096, 6144, 1024, 1024);
        scanT_kernel<<<2048, blk, 0, stream>>>(kvT, aReT, aImT, qT, yT);
        gate_kernel<<<dim3(64, 32, 2), blk, 0, stream>>>(G, yT, gated);
        gemm_kernel<2, 128, 128, 64><<<dim3(32, 8), blk, 0, stream>>>(
            gated, wo + (size_t)i * 1024 * 1024, nullptr,
            x, nullptr, nullptr, nullptr, nullptr, nullptr, 4096, 1024, 1024, 1024);
        rms_f16_kernel<<<4096, blk, 0, stream>>>(x, g2 + i * 1024, xn);
        gemm_kernel<4, 256, 128, 64><<<dim3(16, 32), dim3(512), 0, stream>>>(
            xn, w1 + (size_t)i * 4096 * 1024, b1 + i * 4096,
            nullptr, nullptr, nullptr, nullptr, nullptr, h, 4096, 4096, 1024, 1024);
        // W2 split-K=2, fp16 partials
        gemm_kernel<7, 256, 128, 64><<<dim3(16, 8, 2), dim3(512), 0, stream>>>(
            h, w2 + (size_t)i * 1024 * 4096, nullptr,
            nullptr, nullptr, nullptr, nullptr, nullptr, part, 4096, 1024, 2048, 4096);
        const float* gnext = (i < 3) ? (g1 + (i + 1) * 1024) : gf;
        combine2_rms_kernel<<<4096, blk, 0, stream>>>(part, b2 + i * 1024, gnext, x, xn);
    }

    transpose_f16_kernel<<<dim3(32, 1000, 1), blk, 0, stream>>>(Wl, wl, 1024, 32000, 0);

    // logits: proven 2-barrier kernel (r11/r15: ~315-325us)
    gemm_kernel<0, 256, 128, 64><<<dim3(16, 250), dim3(512), 0, stream>>>(
        xn, wl, nullptr, out, nullptr, nullptr, nullptr, nullptr, nullptr,
        4096, 32000, 1024, 1024);
}

// Round 18
// 1482.681 us; speedup vs baseline: 1.1537x; 1.0367x over previous
//
#include <hip/hip_runtime.h>

// ---------------------------------------------------------------------------
// Transformer (GateLoop-style) forward, MI355X/gfx950.  Round 18.
//  = round 17 + Wo given the proven W2 split-K treatment:
//    - Wo: 256x128 tile, split-K=2 (grid 16x8x2), fp16 partials (EPI 7)
//    - combine_rms<HASBIAS=false> fuses {x += p0+p1 ; xn = rms(x,g2)}
//    - standalone rms_f16 kernel eliminated
//  Established plateau facts: 2-barrier 48KB/3-blocks-per-CU GEMM ~832TF is
//  the structure ceiling at K=1024 (r16/r12/r13/r11 = 490/411/336/315us
//  monotone in occupancy); all deep-pipeline variants exhausted.
// ---------------------------------------------------------------------------

typedef float fx4 __attribute__((ext_vector_type(4)));
typedef _Float16 f16x8 __attribute__((ext_vector_type(8)));
typedef _Float16 f16x4 __attribute__((ext_vector_type(4)));

#define AS1 __attribute__((address_space(1)))
#define AS3 __attribute__((address_space(3)))

// ---------------------------------------------------------------- transpose
__global__ __launch_bounds__(256) void transpose_f16_kernel(
    const float* __restrict__ in, _Float16* __restrict__ out,
    int K, int N, size_t ostride)
{
    __shared__ float tile[32][33];
    const int b = blockIdx.z;
    in  += (size_t)b * K * N;
    out += (size_t)b * ostride;
    const int k0 = blockIdx.x * 32, n0 = blockIdx.y * 32;
    const int tr = threadIdx.x >> 3;
    const int tc = (threadIdx.x & 7) * 4;
    fx4 v = *(const fx4*)&in[(size_t)(k0 + tr) * N + n0 + tc];
    tile[tr][tc + 0] = v[0]; tile[tr][tc + 1] = v[1];
    tile[tr][tc + 2] = v[2]; tile[tr][tc + 3] = v[3];
    __syncthreads();
    f16x4 o;
    #pragma unroll
    for (int e = 0; e < 4; ++e) o[e] = (_Float16)tile[tc + e][tr];
    *(f16x4*)&out[(size_t)(n0 + tr) * K + k0 + tc] = o;
}

// Wqkv transpose with k/v interleave
__global__ __launch_bounds__(256) void transpose_qkv_kernel(
    const float* __restrict__ in, _Float16* __restrict__ out)
{
    __shared__ float tile[32][33];
    const int b = blockIdx.z;
    in  += (size_t)b * 1024 * 3072;
    out += (size_t)b * 6144 * 1024;
    const int k0 = blockIdx.x * 32, n0 = blockIdx.y * 32;
    const int tr = threadIdx.x >> 3;
    const int tc = (threadIdx.x & 7) * 4;
    fx4 v = *(const fx4*)&in[(size_t)(k0 + tr) * 3072 + n0 + tc];
    tile[tr][tc + 0] = v[0]; tile[tr][tc + 1] = v[1];
    tile[tr][tc + 2] = v[2]; tile[tr][tc + 3] = v[3];
    __syncthreads();
    const int col = n0 + tr;
    const int orow = (col < 1024) ? col
                   : (col < 2048) ? 1024 + 2 * (col - 1024)
                                  : 1024 + 2 * (col - 2048) + 1;
    f16x4 o;
    #pragma unroll
    for (int e = 0; e < 4; ++e) o[e] = (_Float16)tile[tc + e][tr];
    *(f16x4*)&out[(size_t)orow * 1024 + k0 + tc] = o;
}

// ---------------------------------------------------------------- row RMS helper
__device__ __forceinline__ float row_rms_scale(float ss) {
    #pragma unroll
    for (int off = 32; off > 0; off >>= 1) ss += __shfl_down(ss, off, 64);
    __shared__ float wsum[4];
    if ((threadIdx.x & 63) == 0) wsum[threadIdx.x >> 6] = ss;
    __syncthreads();
    const float nrm = sqrtf(wsum[0] + wsum[1] + wsum[2] + wsum[3]);
    return 32.0f / fmaxf(nrm, 1e-12f);
}

// ---------------------------------------------------------------- embed + rms
__global__ __launch_bounds__(256) void embed_rms_kernel(
    const int* __restrict__ tokens, const float* __restrict__ emb,
    const float* __restrict__ g, float* __restrict__ x, _Float16* __restrict__ xn)
{
    const int row = blockIdx.x;
    const int t = tokens[row];
    const int c = threadIdx.x * 4;
    fx4 v = *(const fx4*)&emb[(size_t)t * 1024 + c];
    *(fx4*)&x[(size_t)row * 1024 + c] = v;
    const float scale = row_rms_scale(v[0]*v[0] + v[1]*v[1] + v[2]*v[2] + v[3]*v[3]);
    fx4 gg = *(const fx4*)&g[c];
    f16x4 o;
    #pragma unroll
    for (int e = 0; e < 4; ++e) o[e] = (_Float16)(v[e] * scale * gg[e]);
    *(f16x4*)&xn[(size_t)row * 1024 + c] = o;
}

// ---------------------------------------------------------------- gate-loop scan
__device__ __forceinline__ int pidx(int i) { return i + (i >> 5); }

__global__ __launch_bounds__(256) void scanT_kernel(
    const float* __restrict__ kvT, const float* __restrict__ aReT,
    const float* __restrict__ aImT, const float* __restrict__ qT,
    float* __restrict__ yT)
{
    const int tid = threadIdx.x;
    const size_t base = (size_t)blockIdx.x * 2048;
    __shared__ float s_re[2048 + 64], s_im[2048 + 64], s_kv[2048 + 64];

    for (int i = tid; i < 512; i += 256) {
        fx4 kv = *(const fx4*)&kvT[base + i * 4];
        fx4 re = *(const fx4*)&aReT[base + i * 4];
        fx4 im = *(const fx4*)&aImT[base + i * 4];
        #pragma unroll
        for (int e = 0; e < 4; ++e) {
            const int j = pidx(i * 4 + e);
            s_kv[j] = kv[e]; s_re[j] = re[e]; s_im[j] = im[e];
        }
    }
    __syncthreads();

    for (int d = 0; d < 4; ++d) {
        const int half = 1 << d, stride = half << 1;
        const int npairs = 2048 >> (d + 1);
        for (int i = tid; i < npairs; i += 256) {
            const int rj = pidx(i * stride + stride - 1);
            const int lj = pidx(i * stride + stride - 1 - half);
            float lre = s_re[lj], lim = s_im[lj], lkv = s_kv[lj];
            float rre = s_re[rj], rim = s_im[rj], rkv = s_kv[rj];
            s_kv[rj] = rre * lkv + rkv;
            s_re[rj] = rre * lre - rim * lim;
            s_im[rj] = rre * lim + rim * lre;
        }
        __syncthreads();
    }
    if (tid < 64) {
        #pragma unroll
        for (int d = 4; d < 11; ++d) {
            const int half = 1 << d, stride = half << 1;
            const int npairs = 2048 >> (d + 1);
            if (tid < npairs) {
                const int rj = pidx(tid * stride + stride - 1);
                const int lj = pidx(tid * stride + stride - 1 - half);
                float lre = s_re[lj], lim = s_im[lj], lkv = s_kv[lj];
                float rre = s_re[rj], rim = s_im[rj], rkv = s_kv[rj];
                s_kv[rj] = rre * lkv + rkv;
                s_re[rj] = rre * lre - rim * lim;
                s_im[rj] = rre * lim + rim * lre;
            }
        }
        #pragma unroll
        for (int d = 9; d >= 4; --d) {
            const int w = 1 << d;
            const int nupd = (2048 >> (d + 1)) - 1;
            if (tid < nupd) {
                const int i = tid + 1;
                const int rj = pidx((2 * i + 1) * w - 1);
                const int lj = pidx(2 * i * w - 1);
                float lre = s_re[lj], lim = s_im[lj], lkv = s_kv[lj];
                float rre = s_re[rj], rim = s_im[rj], rkv = s_kv[rj];
                s_kv[rj] = rre * lkv + rkv;
                s_re[rj] = rre * lre - rim * lim;
                s_im[rj] = rre * lim + rim * lre;
            }
        }
    }
    __syncthreads();
    for (int d = 3; d >= 0; --d) {
        const int w = 1 << d;
        const int nupd = (2048 >> (d + 1)) - 1;
        for (int t = tid; t < nupd; t += 256) {
            const int i = t + 1;
            const int rj = pidx((2 * i + 1) * w - 1);
            const int lj = pidx(2 * i * w - 1);
            float lre = s_re[lj], lim = s_im[lj], lkv = s_kv[lj];
            float rre = s_re[rj], rim = s_im[rj], rkv = s_kv[rj];
            s_kv[rj] = rre * lkv + rkv;
            s_re[rj] = rre * lre - rim * lim;
            s_im[rj] = rre * lim + rim * lre;
        }
        __syncthreads();
    }
    for (int i = tid; i < 512; i += 256) {
        fx4 q = *(const fx4*)&qT[base + i * 4];
        fx4 o;
        #pragma unroll
        for (int e = 0; e < 4; ++e) o[e] = q[e] * s_kv[pidx(i * 4 + e)];
        *(fx4*)&yT[base + i * 4] = o;
    }
}

// ---------------------------------------------------------------- gating
__global__ __launch_bounds__(256) void gate_kernel(
    const _Float16* __restrict__ G, const float* __restrict__ yT,
    _Float16* __restrict__ gated)
{
    __shared__ float ty[32][33];
    const int n0 = blockIdx.x * 32, h0 = blockIdx.y * 32, b = blockIdx.z;
    const int tr = threadIdx.x >> 3;
    const int tc = (threadIdx.x & 7) * 4;
    fx4 yv = *(const fx4*)&yT[((size_t)b * 1024 + h0 + tr) * 2048 + n0 + tc];
    #pragma unroll
    for (int e = 0; e < 4; ++e) ty[tr][tc + e] = yv[e];
    __syncthreads();
    const size_t grow = ((size_t)b * 2048 + n0 + tr) * 1024 + h0 + tc;
    f16x4 gv = *(const f16x4*)&G[grow];
    f16x4 o;
    #pragma unroll
    for (int e = 0; e < 4; ++e) {
        const float g = (float)gv[e];
        const float s = g / (1.0f + expf(-g));   // silu
        o[e] = (_Float16)(s * ty[tc + e][tr]);
    }
    *(f16x4*)&gated[grow] = o;
}

// ---------------------------------------------------------------- split-K combine + RMS
// x += p0 + p1 (+ bias if HASB); xn = fp16(rms(x) * g).  partials fp16.
template<bool HASB>
__global__ __launch_bounds__(256) void combine_rms_kernel(
    const _Float16* __restrict__ p, const float* __restrict__ bias,
    const float* __restrict__ g, float* __restrict__ x, _Float16* __restrict__ xn)
{
    const int row = blockIdx.x;
    const int c = threadIdx.x * 4;
    const size_t i = (size_t)row * 1024 + c;
    f16x4 a = *(const f16x4*)&p[i];
    f16x4 b = *(const f16x4*)&p[i + (size_t)4096 * 1024];
    fx4 xx = *(const fx4*)&x[i];
    fx4 o;
    if (HASB) {
        fx4 bb = *(const fx4*)&bias[c];
        #pragma unroll
        for (int e = 0; e < 4; ++e) o[e] = xx[e] + ((float)a[e] + (float)b[e] + bb[e]);
    } else {
        #pragma unroll
        for (int e = 0; e < 4; ++e) o[e] = xx[e] + ((float)a[e] + (float)b[e]);
    }
    *(fx4*)&x[i] = o;
    const float scale = row_rms_scale(o[0]*o[0] + o[1]*o[1] + o[2]*o[2] + o[3]*o[3]);
    fx4 gg = *(const fx4*)&g[c];
    f16x4 oh;
    #pragma unroll
    for (int e = 0; e < 4; ++e) oh[e] = (_Float16)(o[e] * scale * gg[e]);
    *(f16x4*)&xn[i] = oh;
}

// ---------------------------------------------------------------- GEMM (2-barrier, proven)
// EPI: 0=store f32 (+bz*M*N), 4=Ch=f16(gelu(v+bias)),
//      6=fused scan-prep routing, 7=Ch=f16(v) (+bz*M*N, split-K partials)
template<int EPI, int BM, int BN, int WTM>
__global__ __launch_bounds__((BM / WTM) * (BN / 64) * 64) void gemm_kernel(
    const _Float16* __restrict__ A, const _Float16* __restrict__ Bt,
    const float* __restrict__ bias,
    float* __restrict__ Cf, float* __restrict__ Cf2, float* __restrict__ Cf3,
    float* __restrict__ aRe, float* __restrict__ aIm,
    _Float16* __restrict__ Ch,
    int M, int N, int K, int Kld)
{
    constexpr int NW      = BN / 64;
    constexpr int THREADS = (BM / WTM) * NW * 64;
    constexpr int M_REP   = WTM / 16;
    __shared__ __align__(16) _Float16 As[BM * 64];
    __shared__ __align__(16) _Float16 Bs[BN * 64];
    const int tid  = threadIdx.x;
    const int lane = tid & 63;
    const int wave = tid >> 6;
    const int bm = blockIdx.x, bn = blockIdx.y;
    const int bz = blockIdx.z;
    const int wm = (wave / NW) * WTM;
    const int wn = (wave % NW) * 64;

    A  += (size_t)bz * K;
    Bt += (size_t)bz * K;
    if (EPI == 0) Cf += (size_t)bz * M * N;
    if (EPI == 7) Ch += (size_t)bz * M * N;

    fx4 acc[M_REP][4] = {};

    const size_t aRow0 = (size_t)bm * BM;
    const size_t bRow0 = (size_t)bn * BN;

    for (int k0 = 0; k0 < K; k0 += 64) {
        constexpr int QA = BM * 8 / THREADS;
        #pragma unroll
        for (int q = 0; q < QA; ++q) {
            const int chunk = q * THREADS + tid;
            const int row = chunk >> 3;
            const int slot = chunk & 7;
            const int gs = slot ^ (row & 7);
            const size_t aoff = (aRow0 + row) * (size_t)Kld + k0 + gs * 8;
            __builtin_amdgcn_global_load_lds((const AS1 void*)(A + aoff),
                (AS3 void*)((char*)As + chunk * 16), 16, 0, 0);
        }
        constexpr int QB = BN * 8 / THREADS;
        #pragma unroll
        for (int q = 0; q < QB; ++q) {
            const int chunk = q * THREADS + tid;
            const int row = chunk >> 3;
            const int slot = chunk & 7;
            const int gs = slot ^ (row & 7);
            const size_t boff = (bRow0 + row) * (size_t)Kld + k0 + gs * 8;
            __builtin_amdgcn_global_load_lds((const AS1 void*)(Bt + boff),
                (AS3 void*)((char*)Bs + chunk * 16), 16, 0, 0);
        }
        __syncthreads();

        #pragma unroll
        for (int kk = 0; kk < 2; ++kk) {
            const int sw = ((kk * 4 + (lane >> 4)) ^ (lane & 7)) * 16;
            f16x8 af[M_REP], bf[4];
            #pragma unroll
            for (int i = 0; i < M_REP; ++i) {
                const int row = wm + i * 16 + (lane & 15);
                af[i] = *(const f16x8*)((const char*)As + row * 128 + sw);
            }
            #pragma unroll
            for (int j = 0; j < 4; ++j) {
                const int row = wn + j * 16 + (lane & 15);
                bf[j] = *(const f16x8*)((const char*)Bs + row * 128 + sw);
            }
            #pragma unroll
            for (int i = 0; i < M_REP; ++i)
                #pragma unroll
                for (int j = 0; j < 4; ++j)
                    acc[i][j] = __builtin_amdgcn_mfma_f32_16x16x32_f16(
                        af[i], bf[j], acc[i][j], 0, 0, 0);
        }
        __syncthreads();
    }

    const int col_l = lane & 15, row_l = (lane >> 4) * 4;
    #pragma unroll
    for (int i = 0; i < M_REP; ++i) {
        #pragma unroll
        for (int j = 0; j < 4; ++j) {
            if (EPI == 6) {
                const int col  = bn * BN + wn + j * 16 + col_l;
                const int row0 = bm * BM + wm + i * 16 + row_l;
                const int b = row0 >> 11;
                const int n = row0 & 2047;
                if (col < 1024) {
                    *(fx4*)&Cf[((size_t)b * 1024 + col) * 2048 + n] = acc[i][j];
                } else if (col < 3072) {
                    fx4 partner;
                    #pragma unroll
                    for (int e = 0; e < 4; ++e)
                        partner[e] = __shfl_xor(acc[i][j][e], 1, 64);
                    if ((col & 1) == 0) {
                        fx4 kv;
                        #pragma unroll
                        for (int e = 0; e < 4; ++e) kv[e] = acc[i][j][e] * partner[e];
                        const int hh = (col - 1024) >> 1;
                        *(fx4*)&Cf2[((size_t)b * 1024 + hh) * 2048 + n] = kv;
                    }
                } else if (col < 5120) {
                    fx4 my;
                    #pragma unroll
                    for (int e = 0; e < 4; ++e) my[e] = acc[i][j][e] + bias[col - 3072];
                    fx4 partner;
                    #pragma unroll
                    for (int e = 0; e < 4; ++e)
                        partner[e] = __shfl_xor(my[e], 1, 64);
                    const bool isRe = (col & 1) == 0;
                    const int hh = (col - 3072) >> 1;
                    fx4 o;
                    #pragma unroll
                    for (int e = 0; e < 4; ++e) {
                        const float re = isRe ? my[e] : partner[e];
                        const float im = isRe ? partner[e] : my[e];
                        const float r = sqrtf(re * re + im * im);
                        const float sg = 1.0f / (1.0f + expf(-r));
                        float a_re, a_im;
                        if (r > 0.0f) { const float inv = sg / r; a_re = re * inv; a_im = im * inv; }
                        else          { a_re = sg; a_im = 0.0f; }
                        o[e] = isRe ? a_re : a_im;
                    }
                    if (isRe) *(fx4*)&aRe[((size_t)b * 1024 + hh) * 2048 + n] = o;
                    else      *(fx4*)&aIm[((size_t)b * 1024 + hh) * 2048 + n] = o;
                } else {
                    #pragma unroll
                    for (int r = 0; r < 4; ++r)
                        Ch[(size_t)(row0 + r) * 1024 + (col - 5120)] = (_Float16)acc[i][j][r];
                }
            } else {
                #pragma unroll
                for (int r = 0; r < 4; ++r) {
                    const int row = bm * BM + wm + i * 16 + row_l + r;
                    const int col = bn * BN + wn + j * 16 + col_l;
                    const float v = acc[i][j][r];
                    if (EPI == 0) {
                        Cf[(size_t)row * N + col] = v;
                    } else if (EPI == 4) {
                        const float t = v + bias[col];
                        const float gelu = 0.5f * t * (1.0f + erff(t * 0.70710678118654752f));
                        Ch[(size_t)row * N + col] = (_Float16)gelu;
                    } else if (EPI == 7) {
                        Ch[(size_t)row * N + col] = (_Float16)v;
                    }
                }
            }
        }
    }
}

// ---------------------------------------------------------------- host
extern "C" void kernel_launch(void* const* d_in, const int* in_sizes, int n_in,
                              void* d_out, int out_size, void* d_ws, size_t ws_size,
                              hipStream_t stream)
{
    const int*   tokens = (const int*)d_in[0];
    const float* emb  = (const float*)d_in[1];
    const float* g1   = (const float*)d_in[2];
    const float* Wqkv = (const float*)d_in[3];
    const float* Wa   = (const float*)d_in[4];
    const float* ba   = (const float*)d_in[5];
    const float* Wg   = (const float*)d_in[6];
    const float* Wo   = (const float*)d_in[7];
    const float* g2   = (const float*)d_in[8];
    const float* W1   = (const float*)d_in[9];
    const float* b1   = (const float*)d_in[10];
    const float* W2   = (const float*)d_in[11];
    const float* b2   = (const float*)d_in[12];
    const float* gf   = (const float*)d_in[13];
    const float* Wl   = (const float*)d_in[14];
    float* out = (float*)d_out;

    char* ws = (char*)d_ws;
    size_t off = 0;
    auto take = [&](size_t bytes) {
        char* p = ws + off; off += (bytes + 255) & ~(size_t)255; return p;
    };

    _Float16* wcat = (_Float16*)take((size_t)4 * 6144 * 1024 * 2);
    _Float16* wo   = (_Float16*)take((size_t)4 * 1024 * 1024 * 2);
    _Float16* w1   = (_Float16*)take((size_t)4 * 4096 * 1024 * 2);
    _Float16* w2   = (_Float16*)take((size_t)4 * 1024 * 4096 * 2);
    char*     wlRegion = take((size_t)64 << 20);
    _Float16* wl   = (_Float16*)wlRegion;
    float*    x    = (float*)take((size_t)4096 * 1024 * 4);
    _Float16* xn   = (_Float16*)take((size_t)4096 * 1024 * 2);
    float*    qkvb = (float*)take((size_t)4096 * 3072 * 4);
    float*    alb  = (float*)take((size_t)4096 * 2048 * 4);
    _Float16* G    = (_Float16*)take((size_t)4096 * 1024 * 2);

    float* qT   = (float*)wlRegion;
    float* kvT  = (float*)(wlRegion + ((size_t)16 << 20));
    float* aReT = (float*)(wlRegion + ((size_t)32 << 20));
    float* aImT = (float*)(wlRegion + ((size_t)48 << 20));
    float*    yT    = alb;                                           // [0,16MiB)
    _Float16* gated = (_Float16*)((char*)alb + ((size_t)16 << 20));  // [16,24MiB)
    _Float16* h     = (_Float16*)qkvb;
    _Float16* part  = (_Float16*)alb;   // fp16 partials 2x8MiB; disjoint from gated

    const dim3 blk(256);

    transpose_qkv_kernel<<<dim3(32, 96, 4), blk, 0, stream>>>(Wqkv, wcat);
    transpose_f16_kernel<<<dim3(32,  64, 4), blk, 0, stream>>>(Wa,   wcat + 3072 * 1024, 1024, 2048, (size_t)6144 * 1024);
    transpose_f16_kernel<<<dim3(32,  32, 4), blk, 0, stream>>>(Wg,   wcat + 5120 * 1024, 1024, 1024, (size_t)6144 * 1024);
    transpose_f16_kernel<<<dim3(32,  32, 4), blk, 0, stream>>>(Wo,   wo,  1024, 1024, (size_t)1024 * 1024);
    transpose_f16_kernel<<<dim3(32, 128, 4), blk, 0, stream>>>(W1,   w1,  1024, 4096, (size_t)4096 * 1024);
    transpose_f16_kernel<<<dim3(128, 32, 4), blk, 0, stream>>>(W2,   w2,  4096, 1024, (size_t)1024 * 4096);

    embed_rms_kernel<<<4096, blk, 0, stream>>>(tokens, emb, g1, x, xn);

    for (int i = 0; i < 4; ++i) {
        gemm_kernel<6, 256, 128, 64><<<dim3(16, 48), dim3(512), 0, stream>>>(
            xn, wcat + (size_t)i * 6144 * 1024, ba + i * 2048,
            qT, kvT, nullptr, aReT, aImT, G, 4096, 6144, 1024, 1024);
        scanT_kernel<<<2048, blk, 0, stream>>>(kvT, aReT, aImT, qT, yT);
        gate_kernel<<<dim3(64, 32, 2), blk, 0, stream>>>(G, yT, gated);
        // Wo: split-K=2, fp16 partials; reads gated [16,24MiB), writes part [0,16MiB)
        gemm_kernel<7, 256, 128, 64><<<dim3(16, 8, 2), dim3(512), 0, stream>>>(
            gated, wo + (size_t)i * 1024 * 1024, nullptr,
            nullptr, nullptr, nullptr, nullptr, nullptr, part, 4096, 1024, 512, 1024);
        combine_rms_kernel<false><<<4096, blk, 0, stream>>>(
            part, nullptr, g2 + i * 1024, x, xn);
        gemm_kernel<4, 256, 128, 64><<<dim3(16, 32), dim3(512), 0, stream>>>(
            xn, w1 + (size_t)i * 4096 * 1024, b1 + i * 4096,
            nullptr, nullptr, nullptr, nullptr, nullptr, h, 4096, 4096, 1024, 1024);
        // W2: split-K=2, fp16 partials
        gemm_kernel<7, 256, 128, 64><<<dim3(16, 8, 2), dim3(512), 0, stream>>>(
            h, w2 + (size_t)i * 1024 * 4096, nullptr,
            nullptr, nullptr, nullptr, nullptr, nullptr, part, 4096, 1024, 2048, 4096);
        const float* gnext = (i < 3) ? (g1 + (i + 1) * 1024) : gf;
        combine_rms_kernel<true><<<4096, blk, 0, stream>>>(
            part, b2 + i * 1024, gnext, x, xn);
    }

    transpose_f16_kernel<<<dim3(32, 1000, 1), blk, 0, stream>>>(Wl, wl, 1024, 32000, 0);

    // logits: proven 2-barrier kernel
    gemm_kernel<0, 256, 128, 64><<<dim3(16, 250), dim3(512), 0, stream>>>(
        xn, wl, nullptr, out, nullptr, nullptr, nullptr, nullptr, nullptr,
        4096, 32000, 1024, 1024);
}